// Round 1
// baseline (271.947 us; speedup 1.0000x reference)
//
#include <hip/hip_runtime.h>

#define H 64
#define NEDGE 50000
#define NNODE 12000

typedef _Float16 f16;
typedef _Float16 h8 __attribute__((ext_vector_type(8)));
typedef float f4 __attribute__((ext_vector_type(4)));

// workspace layout (bytes)
#define O_EH    0ull                 // eh f16 [50000][128]            = 12,800,000
#define O_W2G   12800000ull          // swizzled W2+b2 f16, 258*2048   =  1,056,768
#define O_AGG   13856768ull          // agg f32 [12000][64]            =  3,072,000
#define O_WTIH  16928768ull          // W_ih^T f32 [64][192]           =     49,152
#define O_WTHH  16977920ull          // W_hh^T f32 [64][192]           =     49,152

__device__ __forceinline__ void async16(const void* g, void* l) {
  __builtin_amdgcn_global_load_lds((const __attribute__((address_space(1))) void*)g,
                                   (__attribute__((address_space(3))) void*)l, 16, 0, 0);
}

// ---------------- prep: swizzle W2 (+b2) into MFMA-B-fragment order, transpose GRU weights
// W2g granule index g = ((s*4 + t)*64 + l), 8 f16 each: element i ->
//   s<256:  B value W2[( (s>>2)*64 + t*16+(l&15) )*128 + (s&3)*32 + (l>>4)*8 + i]
//   s>=256: b2[( (s-256)*32 + (l>>4)*8 + i )*64 + t*16+(l&15)]
__global__ __launch_bounds__(256) void k_prep(const float* __restrict__ W2, const float* __restrict__ b2,
                                              const float* __restrict__ Wih, const float* __restrict__ Whh,
                                              f16* __restrict__ w2g, float* __restrict__ wtih, float* __restrict__ wthh) {
  int i = blockIdx.x * 256 + threadIdx.x;
  if (i < 258 * 2048) {
    int ii = i & 7, l = (i >> 3) & 63, t = (i >> 9) & 3, s = i >> 11;
    int n = t * 16 + (l & 15);
    float val;
    if (s < 256) {
      int h = s >> 2;
      int j = (s & 3) * 32 + ((l >> 4) << 3) + ii;
      val = W2[(h * 64 + n) * 128 + j];
    } else {
      int kk = ((s - 256) << 5) + ((l >> 4) << 3) + ii;
      val = b2[kk * 64 + n];
    }
    w2g[i] = (f16)val;
  } else {
    int r = i - 258 * 2048;
    if (r < 12288) {
      int k = r / 192, g = r % 192;
      wtih[r] = Wih[g * 64 + k];
    } else {
      r -= 12288;
      int k = r / 192, g = r % 192;
      wthh[r] = Whh[g * 64 + k];
    }
  }
}

// ---------------- edge MLP: eh = relu(edge @ W1^T + b1) -> f16 [E][128]
__global__ __launch_bounds__(256) void k_edge_mlp(const float* __restrict__ edge, const float* __restrict__ W1,
                                                  const float* __restrict__ b1, f16* __restrict__ ehg) {
  __shared__ float xs[64][68];
  __shared__ float w1s[64][128];  // [k][f]
  __shared__ float b1s[128];
  int t = threadIdx.x;
  long e_base = (long)blockIdx.x * 64;
#pragma unroll
  for (int it = 0; it < 16; ++it) {
    int idx = t + it * 256;
    int e = idx >> 6, k = idx & 63;
    long eg = e_base + e;
    xs[e][k] = (eg < NEDGE) ? edge[eg * 64 + k] : 0.f;
  }
#pragma unroll
  for (int it = 0; it < 32; ++it) {
    int idx = t + it * 256;
    int f = idx >> 6, k = idx & 63;
    w1s[k][f] = W1[idx];  // idx = f*64 + k
  }
  if (t < 128) b1s[t] = b1[t];
  __syncthreads();
  int f0 = (t & 15) * 8, e0 = (t >> 4) * 4;
  float acc[4][8];
#pragma unroll
  for (int i = 0; i < 4; ++i)
#pragma unroll
    for (int j = 0; j < 8; ++j) acc[i][j] = b1s[f0 + j];
#pragma unroll 4
  for (int k = 0; k < 64; ++k) {
    f4 wA = *(const f4*)&w1s[k][f0];
    f4 wB = *(const f4*)&w1s[k][f0 + 4];
#pragma unroll
    for (int i = 0; i < 4; ++i) {
      float x = xs[e0 + i][k];
      acc[i][0] = fmaf(x, wA[0], acc[i][0]); acc[i][1] = fmaf(x, wA[1], acc[i][1]);
      acc[i][2] = fmaf(x, wA[2], acc[i][2]); acc[i][3] = fmaf(x, wA[3], acc[i][3]);
      acc[i][4] = fmaf(x, wB[0], acc[i][4]); acc[i][5] = fmaf(x, wB[1], acc[i][5]);
      acc[i][6] = fmaf(x, wB[2], acc[i][6]); acc[i][7] = fmaf(x, wB[3], acc[i][7]);
    }
  }
#pragma unroll
  for (int i = 0; i < 4; ++i) {
    long eg = e_base + e0 + i;
    if (eg < NEDGE) {
      h8 o;
#pragma unroll
      for (int j = 0; j < 8; ++j) o[j] = (f16)fmaxf(acc[i][j], 0.f);
      *(h8*)&ehg[eg * 128 + f0] = o;
    }
  }
}

// ---------------- main fused GEMM: msg[e,n] = sum_{h,j} v[e,h]*eh[e,j]*W2[h*64+n, j] + sum_h v[e,h]*b2[h*64+n]
// then atomic scatter-add into agg[dst[e]]
__global__ __launch_bounds__(256, 3) void k_msg_gemm(const float* __restrict__ node,
                                                     const int* __restrict__ src, const int* __restrict__ dst,
                                                     const f16* __restrict__ ehg, const f16* __restrict__ w2g,
                                                     float* __restrict__ agg) {
  __shared__ __align__(16) f16 eh_s[64 * 136];   // [e][128+8]
  __shared__ __align__(16) f16 vrow[64 * 72];    // [e][64+8]
  __shared__ __align__(16) f16 vT[64 * 64];      // [h][e]
  __shared__ __align__(16) f16 bbuf[2][4096];    // double-buffered B chunk (8 KB each)
  __shared__ int sdst[64];
  int t = threadIdx.x;
  int e_base = blockIdx.x * 64;

  {  // gather node[src[e]] -> vrow (A-layout for bias steps) + vT (scalar per-step reads)
    int e = t >> 2, q = t & 3;
    int eg = e_base + e;
    bool valid = eg < NEDGE;
    int si = valid ? src[eg] : 0;
    if (q == 0) sdst[e] = valid ? dst[eg] : 0;
    const float* nrow = node + (long)si * 64 + q * 16;
#pragma unroll
    for (int b = 0; b < 4; ++b) {
      f4 vv = {0.f, 0.f, 0.f, 0.f};
      if (valid) vv = *(const f4*)(nrow + b * 4);
#pragma unroll
      for (int m = 0; m < 4; ++m) {
        int c = q * 16 + b * 4 + m;
        f16 hv = (f16)vv[m];
        vrow[e * 72 + c] = hv;
        vT[c * 64 + e] = hv;
      }
    }
  }
#pragma unroll
  for (int it = 0; it < 4; ++it) {  // stage eh tile
    int idx = t + it * 256;
    int e = idx >> 4, g8 = idx & 15;
    int eg = e_base + e;
    uint4 raw = make_uint4(0u, 0u, 0u, 0u);
    if (eg < NEDGE) raw = *(const uint4*)(ehg + (long)eg * 128 + g8 * 8);
    *(uint4*)&eh_s[e * 136 + g8 * 8] = raw;
  }

  const char* w2gb = (const char*)w2g;
  // prologue: async-stage chunk 0
  async16(w2gb + t * 16, (char*)&bbuf[0][0] + t * 16);
  async16(w2gb + 4096 + t * 16, (char*)&bbuf[0][0] + 4096 + t * 16);

  int wave = t >> 6, lane = t & 63;
  int e_l = wave * 16 + (lane & 15);
  int koff = (lane >> 4) * 8;
  f4 acc[4];
#pragma unroll
  for (int i = 0; i < 4; ++i) acc[i] = (f4){0.f, 0.f, 0.f, 0.f};

  const f16* ehp = &eh_s[e_l * 136 + koff];
  const f16* vtp = vT + e_l;

  for (int c = 0; c < 128; ++c) {
    __syncthreads();  // drains chunk-c loads (compiler emits vmcnt(0)) + retires chunk c-1 reads
    {  // prefetch chunk c+1
      const char* g = w2gb + (c + 1) * 8192;
      char* l = (char*)&bbuf[(c + 1) & 1][0];
      async16(g + t * 16, l + t * 16);
      async16(g + 4096 + t * 16, l + 4096 + t * 16);
    }
    const f16* bb = &bbuf[c & 1][0];
    f16 vh = vtp[(c >> 1) << 6];       // v[e, h],  h = c>>1
    const f16* ep = ehp + ((c & 1) << 6);
    const f16* bp = bb + lane * 8;
#pragma unroll
    for (int sl = 0; sl < 2; ++sl) {
      h8 ev = *(const h8*)(ep + sl * 32);
      h8 a = ev * vh;  // 4x v_pk_mul_f16
      acc[0] = __builtin_amdgcn_mfma_f32_16x16x32_f16(a, *(const h8*)(bp + sl * 2048), acc[0], 0, 0, 0);
      acc[1] = __builtin_amdgcn_mfma_f32_16x16x32_f16(a, *(const h8*)(bp + sl * 2048 + 512), acc[1], 0, 0, 0);
      acc[2] = __builtin_amdgcn_mfma_f32_16x16x32_f16(a, *(const h8*)(bp + sl * 2048 + 1024), acc[2], 0, 0, 0);
      acc[3] = __builtin_amdgcn_mfma_f32_16x16x32_f16(a, *(const h8*)(bp + sl * 2048 + 1536), acc[3], 0, 0, 0);
    }
  }
  __syncthreads();  // drains chunk 128 (bias rows, in bbuf[0])
  {
    const f16* bp = &bbuf[0][0] + lane * 8;
#pragma unroll
    for (int sl = 0; sl < 2; ++sl) {
      h8 a = *(const h8*)&vrow[e_l * 72 + sl * 32 + koff];  // A = v  (b2 fold)
      acc[0] = __builtin_amdgcn_mfma_f32_16x16x32_f16(a, *(const h8*)(bp + sl * 2048), acc[0], 0, 0, 0);
      acc[1] = __builtin_amdgcn_mfma_f32_16x16x32_f16(a, *(const h8*)(bp + sl * 2048 + 512), acc[1], 0, 0, 0);
      acc[2] = __builtin_amdgcn_mfma_f32_16x16x32_f16(a, *(const h8*)(bp + sl * 2048 + 1024), acc[2], 0, 0, 0);
      acc[3] = __builtin_amdgcn_mfma_f32_16x16x32_f16(a, *(const h8*)(bp + sl * 2048 + 1536), acc[3], 0, 0, 0);
    }
  }
  // epilogue: C/D layout col=lane&15, row=(lane>>4)*4+reg  -> atomic scatter to agg[dst]
  int lq = lane >> 4, ln = lane & 15;
#pragma unroll
  for (int tt = 0; tt < 4; ++tt)
#pragma unroll
    for (int r = 0; r < 4; ++r) {
      int el = wave * 16 + lq * 4 + r;
      if (e_base + el < NEDGE)
        atomicAdd(&agg[(long)sdst[el] * 64 + tt * 16 + ln], acc[tt][r]);
    }
}

// ---------------- GRU cell + LayerNorm; one wave handles 8 nodes, lane = feature
__global__ __launch_bounds__(256) void k_node(const float* __restrict__ agg, const float* __restrict__ hid,
                                              const float* __restrict__ wtih, const float* __restrict__ wthh,
                                              const float* __restrict__ bih, const float* __restrict__ bhh,
                                              const float* __restrict__ gamma, const float* __restrict__ beta,
                                              float* __restrict__ out) {
  int t = threadIdx.x;
  int wave = t >> 6, lane = t & 63;
  int n0 = blockIdx.x * 32 + wave * 8;
  float x[8], hv[8];
#pragma unroll
  for (int i = 0; i < 8; ++i) {
    x[i] = fmaxf(agg[(long)(n0 + i) * 64 + lane], 0.f);
    hv[i] = hid[(long)(n0 + i) * 64 + lane];
  }
  float gir[8] = {0}, giz[8] = {0}, gin[8] = {0}, ghr[8] = {0}, ghz[8] = {0}, ghn[8] = {0};
  for (int k = 0; k < 64; ++k) {
    float wi0 = wtih[k * 192 + lane], wi1 = wtih[k * 192 + 64 + lane], wi2 = wtih[k * 192 + 128 + lane];
    float wh0 = wthh[k * 192 + lane], wh1 = wthh[k * 192 + 64 + lane], wh2 = wthh[k * 192 + 128 + lane];
#pragma unroll
    for (int i = 0; i < 8; ++i) {
      float xk = __shfl(x[i], k);
      float hk = __shfl(hv[i], k);
      gir[i] = fmaf(wi0, xk, gir[i]); giz[i] = fmaf(wi1, xk, giz[i]); gin[i] = fmaf(wi2, xk, gin[i]);
      ghr[i] = fmaf(wh0, hk, ghr[i]); ghz[i] = fmaf(wh1, hk, ghz[i]); ghn[i] = fmaf(wh2, hk, ghn[i]);
    }
  }
  float bir = bih[lane], biz = bih[64 + lane], bin = bih[128 + lane];
  float bhr = bhh[lane], bhz = bhh[64 + lane], bhn = bhh[128 + lane];
  float gam = gamma[lane], bet = beta[lane];
#pragma unroll
  for (int i = 0; i < 8; ++i) {
    float r = 1.f / (1.f + __expf(-(gir[i] + bir + ghr[i] + bhr)));
    float z = 1.f / (1.f + __expf(-(giz[i] + biz + ghz[i] + bhz)));
    float nn = tanhf(gin[i] + bin + r * (ghn[i] + bhn));
    float o = (1.f - z) * nn + z * hv[i];
    float s = o, s2 = o * o;
#pragma unroll
    for (int d = 1; d < 64; d <<= 1) {
      s += __shfl_xor(s, d);
      s2 += __shfl_xor(s2, d);
    }
    float mu = s * (1.f / 64.f);
    float var = s2 * (1.f / 64.f) - mu * mu;
    out[(long)(n0 + i) * 64 + lane] = (o - mu) * rsqrtf(var + 1e-5f) * gam + bet;
  }
}

extern "C" void kernel_launch(void* const* d_in, const int* in_sizes, int n_in,
                              void* d_out, int out_size, void* d_ws, size_t ws_size,
                              hipStream_t stream) {
  const float* node = (const float*)d_in[0];
  const float* edge = (const float*)d_in[1];
  const float* hid = (const float*)d_in[2];
  const int* src = (const int*)d_in[3];
  const int* dst = (const int*)d_in[4];
  const float* W1 = (const float*)d_in[5];
  const float* b1 = (const float*)d_in[6];
  const float* W2 = (const float*)d_in[7];
  const float* b2 = (const float*)d_in[8];
  const float* Wih = (const float*)d_in[9];
  const float* Whh = (const float*)d_in[10];
  const float* bih = (const float*)d_in[11];
  const float* bhh = (const float*)d_in[12];
  const float* gamma = (const float*)d_in[13];
  const float* beta = (const float*)d_in[14];

  char* ws = (char*)d_ws;
  f16* ehg = (f16*)(ws + O_EH);
  f16* w2g = (f16*)(ws + O_W2G);
  float* agg = (float*)(ws + O_AGG);
  float* wtih = (float*)(ws + O_WTIH);
  float* wthh = (float*)(ws + O_WTHH);

  hipMemsetAsync(agg, 0, (size_t)NNODE * 64 * sizeof(float), stream);
  k_prep<<<2160, 256, 0, stream>>>(W2, b2, Wih, Whh, w2g, wtih, wthh);
  k_edge_mlp<<<782, 256, 0, stream>>>(edge, W1, b1, ehg);
  k_msg_gemm<<<782, 256, 0, stream>>>(node, src, dst, ehg, w2g, agg);
  k_node<<<375, 256, 0, stream>>>(agg, hid, wtih, wthh, bih, bhh, gamma, beta, (float*)d_out);
}

// Round 2
// 213.908 us; speedup vs baseline: 1.2713x; 1.2713x over previous
//
#include <hip/hip_runtime.h>

#define H 64
#define NEDGE 50000
#define NNODE 12000
#define EPAD 50176

typedef _Float16 f16;
typedef _Float16 h8 __attribute__((ext_vector_type(8)));
typedef float f4 __attribute__((ext_vector_type(4)));

// workspace layout (bytes)
#define O_EDGEH 0ull            // edge cast to f16, padded rows zeroed: 50176*64*2 = 6,422,528
#define O_W2G   6422528ull      // swizzled W2 f16 (64 chunks x 16 KB)       = 1,048,576
#define O_W1G   7471104ull      // swizzled W1 f16                           =    16,384
#define O_NB    7487488ull      // nb[i][n] = node[i,:] @ b2mat  f32         = 3,072,000
#define O_AGG   10559488ull     // agg f32 [12000][64]                       = 3,072,000
#define O_WTIH  13631488ull     // W_ih^T f32 [64][192]                      =    49,152
#define O_WTHH  13680640ull     // W_hh^T f32 [64][192]                      =    49,152

__device__ __forceinline__ void async16(const void* g, void* l) {
  __builtin_amdgcn_global_load_lds((const __attribute__((address_space(1))) void*)g,
                                   (__attribute__((address_space(3))) void*)l, 16, 0, 0);
}

// ---------------- prep: edge->f16 (padded), W2/W1 -> MFMA-B granule order, GRU weight transpose, nb GEMM
// w2g element: id = (((h*4+s)*4+t)*64+l)*8+i  ->  W2[(h*64 + t*16+(l&15))*128 + s*32+(l>>4)*8+i]
// w1g element: id = ((s*8+t)*64+l)*8+i        ->  W1[(t*16+(l&15))*64 + s*32+(l>>4)*8+i]
__global__ __launch_bounds__(256) void k_prep(const float* __restrict__ edge, const float* __restrict__ W1,
                                              const float* __restrict__ W2, const float* __restrict__ b2,
                                              const float* __restrict__ node,
                                              const float* __restrict__ Wih, const float* __restrict__ Whh,
                                              f16* __restrict__ edgeh, f16* __restrict__ w1g, f16* __restrict__ w2g,
                                              float* __restrict__ nb, float* __restrict__ wtih, float* __restrict__ wthh) {
  __shared__ float bs[64][65];
  __shared__ float xs[64][65];
  int bid = blockIdx.x;
  if (bid < 14720) {  // elementwise part: 3,768,320 elements
    int id = bid * 256 + threadIdx.x;
    if (id < 3211264) {
      edgeh[id] = (id < NEDGE * 64) ? (f16)edge[id] : (f16)0.f;
      return;
    }
    id -= 3211264;
    if (id < 524288) {
      int ii = id & 7, l = (id >> 3) & 63, t4 = (id >> 9) & 3, s = (id >> 11) & 3, h = id >> 13;
      int n = t4 * 16 + (l & 15), j = s * 32 + ((l >> 4) << 3) + ii;
      w2g[id] = (f16)W2[(h * 64 + n) * 128 + j];
      return;
    }
    id -= 524288;
    if (id < 8192) {
      int ii = id & 7, l = (id >> 3) & 63, tt = (id >> 9) & 7, s = id >> 12;
      int n = tt * 16 + (l & 15), k = s * 32 + ((l >> 4) << 3) + ii;
      w1g[id] = (f16)W1[n * 64 + k];
      return;
    }
    id -= 8192;
    if (id < 12288) {
      int k = id / 192, g = id % 192;
      wtih[id] = Wih[g * 64 + k];
      return;
    }
    id -= 12288;
    if (id < 12288) {
      int k = id / 192, g = id % 192;
      wthh[id] = Whh[g * 64 + k];
    }
    return;
  }
  // nb part: 188 blocks x 64 nodes: nb[i][n] = sum_a node[i][a] * b2[a*64+n]
  int t = threadIdx.x;
  int n0 = (bid - 14720) * 64;
#pragma unroll
  for (int it = 0; it < 16; ++it) {
    int idx = t + it * 256;
    int rr = idx >> 6, cc = idx & 63;
    bs[rr][cc] = b2[idx];
    int nn = n0 + rr;
    xs[rr][cc] = (nn < NNODE) ? node[(long)nn * 64 + cc] : 0.f;
  }
  __syncthreads();
  int f0 = (t & 15) * 4, e0 = (t >> 4) * 4;
  float acc[4][4] = {};
#pragma unroll 4
  for (int k = 0; k < 64; ++k) {
    f4 w = *(const f4*)&bs[k][f0];
#pragma unroll
    for (int i = 0; i < 4; ++i) {
      float x = xs[e0 + i][k];
      acc[i][0] = fmaf(x, w[0], acc[i][0]); acc[i][1] = fmaf(x, w[1], acc[i][1]);
      acc[i][2] = fmaf(x, w[2], acc[i][2]); acc[i][3] = fmaf(x, w[3], acc[i][3]);
    }
  }
#pragma unroll
  for (int i = 0; i < 4; ++i) {
    int nn = n0 + e0 + i;
    if (nn < NNODE)
#pragma unroll
      for (int j = 0; j < 4; ++j) nb[(long)nn * 64 + f0 + j] = acc[i][j];
  }
}

// ---------------- fused: edge-MLP (f16 MFMA) -> P=v(x)eh GEMM vs W2 (K=8192, B streamed) -> +nb -> atomic scatter
// block: 128 edges, 4 waves 2x2 (wave: M=64 rows, N=32 cols). eh fragments live in registers for the K-loop.
__global__ __launch_bounds__(256, 2) void k_msg(const float* __restrict__ node,
                                                const int* __restrict__ src, const int* __restrict__ dst,
                                                const f16* __restrict__ edgeh, const f16* __restrict__ w1g,
                                                const f16* __restrict__ w2g, const float* __restrict__ b1,
                                                const float* __restrict__ nb, float* __restrict__ agg) {
  // LDS map (67072 B total):
  //  [0,16384)      est   (phase 0-1a)  | bbuf[0] (phase 3)
  //  [16384,32768)  eh_s lower half     | bbuf[1] (phase 3)
  //  [16384,49152)  eh_s (phase 1b-2)
  //  [49152,65536)  vT f16 [64 h][128 e]
  //  [65536,66048)  ssrc, [66048,66560) sdst, [66560,67072) b1s
  __shared__ __align__(16) char lds[67072];
  f16* est = (f16*)lds;
  f16* eh_s = (f16*)(lds + 16384);
  f16* bbuf = (f16*)lds;
  f16* vT = (f16*)(lds + 49152);
  int* ssrc = (int*)(lds + 65536);
  int* sdst = (int*)(lds + 66048);
  float* b1s = (float*)(lds + 66560);

  int t = threadIdx.x;
  int e_base = blockIdx.x * 128;

  // ---- phase 0: indices, b1, edge tile (async, swizzled granules), v gather -> vT
  if (t < 128) {
    int eg = e_base + t;
    bool valid = eg < NEDGE;
    ssrc[t] = valid ? src[eg] : 0;
    sdst[t] = valid ? dst[eg] : 0;
  } else {
    b1s[t - 128] = b1[t - 128];
  }
  {
    const char* ehb = (const char*)edgeh;
#pragma unroll
    for (int r = 0; r < 4; ++r) {
      int idx = r * 256 + t;
      int e = idx >> 3, c1 = idx & 7;
      int c = c1 ^ (e & 7);  // stored swizzled: lds granule (e,c1) <- global granule (e, c1^(e&7))
      async16(ehb + ((long)(e_base + e) * 8 + c) * 16, (char*)est + idx * 16);
    }
  }
  {
    int e = t >> 1, half = t & 1;
    int eg = e_base + e;
    int si = (eg < NEDGE) ? src[eg] : 0;
    const f4* nr = (const f4*)(node + (long)si * 64 + half * 32);
#pragma unroll
    for (int b = 0; b < 8; ++b) {
      f4 vv = nr[b];
#pragma unroll
      for (int m = 0; m < 4; ++m) vT[(half * 32 + b * 4 + m) * 128 + e] = (f16)vv[m];
    }
  }
  __syncthreads();

  int wave = t >> 6, lane = t & 63;
  int mh = wave & 1, nh = wave >> 1;
  int l15 = lane & 15, lq = lane >> 4;

  // ---- phase 1a: eh = relu(edge @ W1^T + b1) via MFMA (M=128,N=128,K=64), wave tile 64x64
  h8 afr[4][2];
#pragma unroll
  for (int g = 0; g < 4; ++g) {
    int eg = mh * 64 + g * 16 + l15;
#pragma unroll
    for (int s = 0; s < 2; ++s) {
      int c = (s * 4 + lq) ^ (eg & 7);
      afr[g][s] = *(const h8*)(est + (eg * 8 + c) * 8);
    }
  }
  h8 bfr[2][4];
#pragma unroll
  for (int s = 0; s < 2; ++s)
#pragma unroll
    for (int tt = 0; tt < 4; ++tt)
      bfr[s][tt] = *(const h8*)(w1g + ((s * 8 + nh * 4 + tt) * 64 + lane) * 8);
  f4 acc_eh[4][4];
#pragma unroll
  for (int g = 0; g < 4; ++g)
#pragma unroll
    for (int tt = 0; tt < 4; ++tt) acc_eh[g][tt] = (f4){0.f, 0.f, 0.f, 0.f};
#pragma unroll
  for (int s = 0; s < 2; ++s)
#pragma unroll
    for (int g = 0; g < 4; ++g)
#pragma unroll
      for (int tt = 0; tt < 4; ++tt)
        acc_eh[g][tt] = __builtin_amdgcn_mfma_f32_16x16x32_f16(afr[g][s], bfr[s][tt], acc_eh[g][tt], 0, 0, 0);
  __syncthreads();  // est dead; safe to start B pipeline into bbuf[0]

  const char* w2b = (const char*)w2g;
#pragma unroll
  for (int r = 0; r < 4; ++r) async16(w2b + r * 4096 + t * 16, (char*)bbuf + r * 4096 + t * 16);

  // ---- phase 1b: write eh tile to LDS (swizzled granules), with relu + b1
#pragma unroll
  for (int g = 0; g < 4; ++g)
#pragma unroll
    for (int tt = 0; tt < 4; ++tt) {
      int n = nh * 64 + tt * 16 + l15;
      int jg = n >> 3;
#pragma unroll
      for (int r = 0; r < 4; ++r) {
        int e = mh * 64 + g * 16 + lq * 4 + r;
        float val = fmaxf(acc_eh[g][tt][r] + b1s[n], 0.f);
        eh_s[(e * 16 + (jg ^ (e & 15))) * 8 + (n & 7)] = (f16)val;
      }
    }
  __syncthreads();

  // ---- phase 2: eh fragments -> registers (j = s*32 + lq*8 + i, period-128 in K)
  h8 ehreg[4][4];
#pragma unroll
  for (int g = 0; g < 4; ++g) {
    int eg = mh * 64 + g * 16 + l15;
#pragma unroll
    for (int s = 0; s < 4; ++s) {
      int jg = (s * 4 + lq) ^ (eg & 15);
      ehreg[g][s] = *(const h8*)(eh_s + (eg * 16 + jg) * 8);
    }
  }
  __syncthreads();  // eh_s dead; bbuf[1] may now be written

  // ---- phase 3: K-loop over 64 h-chunks (K=128 each), B double-buffered via global_load_lds
  f4 acc[4][2];
#pragma unroll
  for (int g = 0; g < 4; ++g) {
    acc[g][0] = (f4){0.f, 0.f, 0.f, 0.f};
    acc[g][1] = (f4){0.f, 0.f, 0.f, 0.f};
  }
  for (int h = 0; h < 64; ++h) {
    __syncthreads();  // drains prefetch of chunk h, retires reads of the buffer being overwritten
    {
      const char* gsrc = w2b + (h + 1) * 16384;  // h=63 overreads into w1g region: harmless, unused
      char* ldst = (char*)bbuf + ((h + 1) & 1) * 16384;
#pragma unroll
      for (int r = 0; r < 4; ++r) async16(gsrc + r * 4096 + t * 16, ldst + r * 4096 + t * 16);
    }
    const f16* bb = bbuf + (h & 1) * 8192;
    f16 vh[4];
#pragma unroll
    for (int g = 0; g < 4; ++g) vh[g] = vT[h * 128 + mh * 64 + g * 16 + l15];
#pragma unroll
    for (int s = 0; s < 4; ++s) {
      h8 bf0 = *(const h8*)(bb + ((s * 4 + nh * 2) * 64 + lane) * 8);
      h8 bf1 = *(const h8*)(bb + ((s * 4 + nh * 2 + 1) * 64 + lane) * 8);
#pragma unroll
      for (int g = 0; g < 4; ++g) {
        h8 a = ehreg[g][s] * vh[g];
        acc[g][0] = __builtin_amdgcn_mfma_f32_16x16x32_f16(a, bf0, acc[g][0], 0, 0, 0);
        acc[g][1] = __builtin_amdgcn_mfma_f32_16x16x32_f16(a, bf1, acc[g][1], 0, 0, 0);
      }
    }
  }

  // ---- epilogue: + nb[src], atomic scatter to agg[dst]
#pragma unroll
  for (int g = 0; g < 4; ++g)
#pragma unroll
    for (int t2 = 0; t2 < 2; ++t2)
#pragma unroll
      for (int r = 0; r < 4; ++r) {
        int el = mh * 64 + g * 16 + lq * 4 + r;
        if (e_base + el < NEDGE) {
          int n = nh * 32 + t2 * 16 + l15;
          float v = acc[g][t2][r] + nb[(long)ssrc[el] * 64 + n];
          atomicAdd(&agg[(long)sdst[el] * 64 + n], v);
        }
      }
}

// ---------------- GRU cell + LayerNorm; one wave handles 8 nodes, lane = feature
__global__ __launch_bounds__(256) void k_node(const float* __restrict__ agg, const float* __restrict__ hid,
                                              const float* __restrict__ wtih, const float* __restrict__ wthh,
                                              const float* __restrict__ bih, const float* __restrict__ bhh,
                                              const float* __restrict__ gamma, const float* __restrict__ beta,
                                              float* __restrict__ out) {
  int t = threadIdx.x;
  int wave = t >> 6, lane = t & 63;
  int n0 = blockIdx.x * 32 + wave * 8;
  float x[8], hv[8];
#pragma unroll
  for (int i = 0; i < 8; ++i) {
    x[i] = fmaxf(agg[(long)(n0 + i) * 64 + lane], 0.f);
    hv[i] = hid[(long)(n0 + i) * 64 + lane];
  }
  float gir[8] = {0}, giz[8] = {0}, gin[8] = {0}, ghr[8] = {0}, ghz[8] = {0}, ghn[8] = {0};
  for (int k = 0; k < 64; ++k) {
    float wi0 = wtih[k * 192 + lane], wi1 = wtih[k * 192 + 64 + lane], wi2 = wtih[k * 192 + 128 + lane];
    float wh0 = wthh[k * 192 + lane], wh1 = wthh[k * 192 + 64 + lane], wh2 = wthh[k * 192 + 128 + lane];
#pragma unroll
    for (int i = 0; i < 8; ++i) {
      float xk = __shfl(x[i], k);
      float hk = __shfl(hv[i], k);
      gir[i] = fmaf(wi0, xk, gir[i]); giz[i] = fmaf(wi1, xk, giz[i]); gin[i] = fmaf(wi2, xk, gin[i]);
      ghr[i] = fmaf(wh0, hk, ghr[i]); ghz[i] = fmaf(wh1, hk, ghz[i]); ghn[i] = fmaf(wh2, hk, ghn[i]);
    }
  }
  float bir = bih[lane], biz = bih[64 + lane], bin = bih[128 + lane];
  float bhr = bhh[lane], bhz = bhh[64 + lane], bhn = bhh[128 + lane];
  float gam = gamma[lane], bet = beta[lane];
#pragma unroll
  for (int i = 0; i < 8; ++i) {
    float r = 1.f / (1.f + __expf(-(gir[i] + bir + ghr[i] + bhr)));
    float z = 1.f / (1.f + __expf(-(giz[i] + biz + ghz[i] + bhz)));
    float nn = tanhf(gin[i] + bin + r * (ghn[i] + bhn));
    float o = (1.f - z) * nn + z * hv[i];
    float s = o, s2 = o * o;
#pragma unroll
    for (int d = 1; d < 64; d <<= 1) {
      s += __shfl_xor(s, d);
      s2 += __shfl_xor(s2, d);
    }
    float mu = s * (1.f / 64.f);
    float var = s2 * (1.f / 64.f) - mu * mu;
    out[(long)(n0 + i) * 64 + lane] = (o - mu) * rsqrtf(var + 1e-5f) * gam + bet;
  }
}

extern "C" void kernel_launch(void* const* d_in, const int* in_sizes, int n_in,
                              void* d_out, int out_size, void* d_ws, size_t ws_size,
                              hipStream_t stream) {
  const float* node = (const float*)d_in[0];
  const float* edge = (const float*)d_in[1];
  const float* hid = (const float*)d_in[2];
  const int* src = (const int*)d_in[3];
  const int* dst = (const int*)d_in[4];
  const float* W1 = (const float*)d_in[5];
  const float* b1 = (const float*)d_in[6];
  const float* W2 = (const float*)d_in[7];
  const float* b2 = (const float*)d_in[8];
  const float* Wih = (const float*)d_in[9];
  const float* Whh = (const float*)d_in[10];
  const float* bih = (const float*)d_in[11];
  const float* bhh = (const float*)d_in[12];
  const float* gamma = (const float*)d_in[13];
  const float* beta = (const float*)d_in[14];

  char* ws = (char*)d_ws;
  f16* edgeh = (f16*)(ws + O_EDGEH);
  f16* w2g = (f16*)(ws + O_W2G);
  f16* w1g = (f16*)(ws + O_W1G);
  float* nb = (float*)(ws + O_NB);
  float* agg = (float*)(ws + O_AGG);
  float* wtih = (float*)(ws + O_WTIH);
  float* wthh = (float*)(ws + O_WTHH);

  hipMemsetAsync(agg, 0, (size_t)NNODE * 64 * sizeof(float), stream);
  k_prep<<<14908, 256, 0, stream>>>(edge, W1, W2, b2, node, Wih, Whh, edgeh, w1g, w2g, nb, wtih, wthh);
  k_msg<<<391, 256, 0, stream>>>(node, src, dst, edgeh, w1g, w2g, b1, nb, agg);
  k_node<<<375, 256, 0, stream>>>(agg, hid, wtih, wthh, bih, bhh, gamma, beta, (float*)d_out);
}